// Round 1
// 449.255 us; speedup vs baseline: 1.0915x; 1.0915x over previous
//
#include <hip/hip_runtime.h>
#include <hip/hip_bf16.h>

#define N_NODES 100000
#define N_EDGES 1600000
#define N_EL    200000
// D_IN = D_HID = 128; layer-3 output D = 64. f32 inputs, int32 indices, f32 output.
// Round 16:
//  (1) gather kernels: bulk per-lane col load (64/row) + LDS broadcast -> all
//      t-gathers issue back-to-back (2 RTs/row instead of ~4), dinv[src] folded
//      in via fma (free), zero-padded batches (no tail loop), NT output stores.
//  (2) dinv removed from GEMM epilogue -> GEMM1 independent of CSR build ->
//      k_fat1 merges rank (atomic-bound) with GEMM1 (MFMA/BW-bound) in one
//      dispatch; rank hides under the GEMM.

#define NB_SCAN ((N_NODES + 255) / 256)   // 391
#define CPAD 16                            // ints per counter line
#define GT_GEMM ((N_NODES + 63) / 64)      // 1563 gemm blocks (64 rows each)

typedef unsigned int uint32;
typedef unsigned short ushort16;
typedef __attribute__((ext_vector_type(8))) short short8;   // 8 bf16 (4 VGPRs)
typedef __attribute__((ext_vector_type(4))) float f32x4;

static __device__ __forceinline__ ushort16 f2bf(float f) {
    uint32 u = __float_as_uint(f);
    u += 0x7fffu + ((u >> 16) & 1u);      // RNE
    return (ushort16)(u >> 16);
}
static __device__ __forceinline__ float bf_lo(uint32 p) { return __uint_as_float(p << 16); }
static __device__ __forceinline__ float bf_hi(uint32 p) { return __uint_as_float(p & 0xffff0000u); }
static __device__ __forceinline__ float bf2f(ushort16 h) { return __uint_as_float((uint32)h << 16); }

// ---------------- scan pass 1 (+ dinv); deg read from padded counters ----------------
__global__ void k_scan1(const int* __restrict__ cpad, int* __restrict__ rowptr,
                        int* __restrict__ bsum, float* __restrict__ dinv) {
    __shared__ int s[256];
    int t = threadIdx.x;
    int i = blockIdx.x * 256 + t;
    int v = (i < N_NODES) ? cpad[(size_t)i * CPAD] : 0;
    if (i < N_NODES) dinv[i] = 1.0f / sqrtf((float)(v + 1));   // +1 self-loop
    s[t] = v;
    __syncthreads();
    for (int off = 1; off < 256; off <<= 1) {
        int u = (t >= off) ? s[t - off] : 0;
        __syncthreads();
        s[t] += u;
        __syncthreads();
    }
    if (i < N_NODES) rowptr[i] = s[t] - v;          // exclusive, local
    if (t == 255) bsum[blockIdx.x] = s[255];
}

__global__ void k_scan2(const int* __restrict__ bsum, int* __restrict__ boff) {
    __shared__ int s[512];
    int t = threadIdx.x;
    int v = (t < NB_SCAN) ? bsum[t] : 0;
    s[t] = v;
    __syncthreads();
    for (int off = 1; off < 512; off <<= 1) {
        int u = (t >= off) ? s[t - off] : 0;
        __syncthreads();
        s[t] += u;
        __syncthreads();
    }
    if (t < NB_SCAN) boff[t] = s[t] - v;            // exclusive
    if (t == NB_SCAN - 1) boff[NB_SCAN] = s[t];     // total
}

__global__ void k_scan3(int* __restrict__ rowptr, const int* __restrict__ boff) {
    int i = blockIdx.x * 256 + threadIdx.x;
    if (i < N_NODES) rowptr[i] += boff[blockIdx.x];
    if (i == 0) rowptr[N_NODES] = boff[NB_SCAN];
}

// ---------------- pass 2: atomic-free CSR fill ----------------
__global__ void k_fill2(const int* __restrict__ src, const int* __restrict__ dst,
                        const int* __restrict__ rowptr, const int* __restrict__ r,
                        int* __restrict__ col) {
    int e = blockIdx.x * blockDim.x + threadIdx.x;
    if (e >= N_EDGES) return;
    int pos = rowptr[dst[e]] + r[e];
    __builtin_nontemporal_store(src[e], &col[pos]);
}

// ---------------- A-fragment loaders ----------------
static __device__ __forceinline__ short8 load_afrag(const float* arow, int off) {
    float4 a0 = *(const float4*)(arow + off);
    float4 a1 = *(const float4*)(arow + off + 4);
    short8 af;
    af[0] = (short)f2bf(a0.x); af[1] = (short)f2bf(a0.y);
    af[2] = (short)f2bf(a0.z); af[3] = (short)f2bf(a0.w);
    af[4] = (short)f2bf(a1.x); af[5] = (short)f2bf(a1.y);
    af[6] = (short)f2bf(a1.z); af[7] = (short)f2bf(a1.w);
    return af;
}
static __device__ __forceinline__ short8 load_afrag(const ushort16* arow, int off) {
    return *(const short8*)(arow + off);   // 16B aligned
}

// ---------------- MFMA GEMM body: t[n,:] = bf16( A[n,:128] @ W[128,D] ) ----------
// (no dinv scaling here any more; it is folded into the gather)
template <int D, typename AT>
static __device__ __forceinline__ void gemm_body(int bid, const AT* __restrict__ A,
        const float* __restrict__ W, ushort16* __restrict__ C) {
    constexpr int NT = D / 16;                 // 8 (D=128) or 4 (D=64)
    __shared__ short sB[4 * NT * 64 * 8];      // 32 KB / 16 KB

    int tid = threadIdx.x;

    // stage W -> LDS in B-fragment order
    for (int idx = tid; idx < 128 * D; idx += 256) {
        int k = idx / D;
        int n = idx % D;
        int kt = k >> 5, kr = k & 31;
        int q = kr >> 3, j = kr & 7;
        int nt = n >> 4, nn = n & 15;
        sB[(((kt * NT + nt) * 64) + q * 16 + nn) * 8 + j] = (short)f2bf(W[idx]);
    }
    __syncthreads();

    int w = tid >> 6;
    int l = tid & 63;
    int q = l >> 4;
    int nn15 = l & 15;
    int m0 = bid * 64 + w * 16;

    f32x4 acc[NT];
#pragma unroll
    for (int i = 0; i < NT; ++i) acc[i] = (f32x4){0.f, 0.f, 0.f, 0.f};

    int m = m0 + nn15;
    m = min(m, N_NODES - 1);                    // tail clamp (loads only)
    const AT* arow = A + (size_t)m * 128;

#pragma unroll
    for (int kt = 0; kt < 4; ++kt) {
        short8 af = load_afrag(arow, kt * 32 + q * 8);
#pragma unroll
        for (int nt = 0; nt < NT; ++nt) {
            short8 bf = *(const short8*)&sB[((kt * NT + nt) * 64 + l) * 8];
            acc[nt] = __builtin_amdgcn_mfma_f32_16x16x32_bf16(af, bf, acc[nt], 0, 0, 0);
        }
    }

    // epilogue: node = m0 + q*4 + r, col = nt*16 + nn15
#pragma unroll
    for (int nt = 0; nt < NT; ++nt) {
#pragma unroll
        for (int r = 0; r < 4; ++r) {
            int node = m0 + q * 4 + r;
            if (node < N_NODES)
                C[(size_t)node * D + nt * 16 + nn15] = f2bf(acc[nt][r]);
        }
    }
}

template <int D, typename AT>
__global__ __launch_bounds__(256, 4) void k_gemm_mfma(const AT* __restrict__ A,
        const float* __restrict__ W, ushort16* __restrict__ C) {
    gemm_body<D, AT>(blockIdx.x, A, W, C);
}

// ---------------- fat kernel: GEMM1 (blocks [0,GT_GEMM)) + rank (rest) ----------
__global__ __launch_bounds__(256, 4) void k_fat1(const float* __restrict__ A,
        const float* __restrict__ W, ushort16* __restrict__ C,
        const int* __restrict__ dst, int* __restrict__ cpad, int* __restrict__ r) {
    if (blockIdx.x < GT_GEMM) {
        gemm_body<128, float>(blockIdx.x, A, W, C);
    } else {
        int e = (blockIdx.x - GT_GEMM) * 256 + threadIdx.x;
        if (e < N_EDGES) r[e] = atomicAdd(&cpad[(size_t)dst[e] * CPAD], 1);
    }
}

// ---------------- gather, D=128: one wave/node, bulk-col + LDS broadcast ---------
// out[dst] = dinv[dst] * ( dinv[dst]*g[dst] + sum_src dinv[src]*g[src] ) + b
template <bool RELU>
__global__ void k_gather128(const int* __restrict__ rowptr, const int* __restrict__ col,
                            const float* __restrict__ dinv, const uint32* __restrict__ t,
                            const float* __restrict__ b, uint32* __restrict__ outbuf) {
    __shared__ int   sc[4][64];
    __shared__ float sd[4][64];
    int tid = threadIdx.x;
    unsigned wid = (blockIdx.x * 256u + tid) >> 6;
    if (wid >= N_NODES) return;
    int w = tid >> 6;
    int lane = tid & 63;
    int beg = rowptr[wid], end = rowptr[wid + 1];
    float di = dinv[wid];
    uint32 p = t[(size_t)wid * 64 + lane];
    float ax = di * bf_lo(p), ay = di * bf_hi(p);        // self-loop term
    for (int base = beg; base < end; base += 64) {
        int cnt = min(end - base, 64);
        int c = 0;
        if (lane < cnt) c = col[base + lane];            // 1 coalesced load / 64 edges
        sc[w][lane] = c;
        float cd = (lane < cnt) ? dinv[c] : 0.f;         // per-src norm (0 pads batches)
        sd[w][lane] = cd;
        int nb = (cnt + 7) >> 3;                          // zero-padded 8-batches
        for (int j8 = 0; j8 < nb; ++j8) {
            int j = j8 << 3;
            int s0 = sc[w][j+0], s1 = sc[w][j+1], s2 = sc[w][j+2], s3 = sc[w][j+3];
            int s4 = sc[w][j+4], s5 = sc[w][j+5], s6 = sc[w][j+6], s7 = sc[w][j+7];
            uint32 v0 = t[(size_t)s0 * 64 + lane];
            uint32 v1 = t[(size_t)s1 * 64 + lane];
            uint32 v2 = t[(size_t)s2 * 64 + lane];
            uint32 v3 = t[(size_t)s3 * 64 + lane];
            uint32 v4 = t[(size_t)s4 * 64 + lane];
            uint32 v5 = t[(size_t)s5 * 64 + lane];
            uint32 v6 = t[(size_t)s6 * 64 + lane];
            uint32 v7 = t[(size_t)s7 * 64 + lane];
            float d0 = sd[w][j+0], d1 = sd[w][j+1], d2 = sd[w][j+2], d3 = sd[w][j+3];
            float d4 = sd[w][j+4], d5 = sd[w][j+5], d6 = sd[w][j+6], d7 = sd[w][j+7];
            ax = fmaf(d0, bf_lo(v0), ax); ay = fmaf(d0, bf_hi(v0), ay);
            ax = fmaf(d1, bf_lo(v1), ax); ay = fmaf(d1, bf_hi(v1), ay);
            ax = fmaf(d2, bf_lo(v2), ax); ay = fmaf(d2, bf_hi(v2), ay);
            ax = fmaf(d3, bf_lo(v3), ax); ay = fmaf(d3, bf_hi(v3), ay);
            ax = fmaf(d4, bf_lo(v4), ax); ay = fmaf(d4, bf_hi(v4), ay);
            ax = fmaf(d5, bf_lo(v5), ax); ay = fmaf(d5, bf_hi(v5), ay);
            ax = fmaf(d6, bf_lo(v6), ax); ay = fmaf(d6, bf_hi(v6), ay);
            ax = fmaf(d7, bf_lo(v7), ax); ay = fmaf(d7, bf_hi(v7), ay);
        }
    }
    float2 bb = ((const float2*)b)[lane];
    float ox = di * ax + bb.x;
    float oy = di * ay + bb.y;
    if (RELU) { ox = fmaxf(ox, 0.f); oy = fmaxf(oy, 0.f); }
    __builtin_nontemporal_store((uint32)f2bf(ox) | ((uint32)f2bf(oy) << 16),
                                &outbuf[(size_t)wid * 64 + lane]);
}

// ---------------- gather, D=64: same structure, bf16 scalar per lane -------------
template <bool RELU>
__global__ void k_gather64(const int* __restrict__ rowptr, const int* __restrict__ col,
                           const float* __restrict__ dinv, const ushort16* __restrict__ t,
                           const float* __restrict__ b, ushort16* __restrict__ outbuf) {
    __shared__ int   sc[4][64];
    __shared__ float sd[4][64];
    int tid = threadIdx.x;
    unsigned wid = (blockIdx.x * 256u + tid) >> 6;
    if (wid >= N_NODES) return;
    int w = tid >> 6;
    int lane = tid & 63;
    int beg = rowptr[wid], end = rowptr[wid + 1];
    float di = dinv[wid];
    float acc = di * bf2f(t[(size_t)wid * 64 + lane]);   // self-loop term
    for (int base = beg; base < end; base += 64) {
        int cnt = min(end - base, 64);
        int c = 0;
        if (lane < cnt) c = col[base + lane];
        sc[w][lane] = c;
        float cd = (lane < cnt) ? dinv[c] : 0.f;
        sd[w][lane] = cd;
        int nb = (cnt + 7) >> 3;
        for (int j8 = 0; j8 < nb; ++j8) {
            int j = j8 << 3;
            int s0 = sc[w][j+0], s1 = sc[w][j+1], s2 = sc[w][j+2], s3 = sc[w][j+3];
            int s4 = sc[w][j+4], s5 = sc[w][j+5], s6 = sc[w][j+6], s7 = sc[w][j+7];
            float v0 = bf2f(t[(size_t)s0 * 64 + lane]);
            float v1 = bf2f(t[(size_t)s1 * 64 + lane]);
            float v2 = bf2f(t[(size_t)s2 * 64 + lane]);
            float v3 = bf2f(t[(size_t)s3 * 64 + lane]);
            float v4 = bf2f(t[(size_t)s4 * 64 + lane]);
            float v5 = bf2f(t[(size_t)s5 * 64 + lane]);
            float v6 = bf2f(t[(size_t)s6 * 64 + lane]);
            float v7 = bf2f(t[(size_t)s7 * 64 + lane]);
            float d0 = sd[w][j+0], d1 = sd[w][j+1], d2 = sd[w][j+2], d3 = sd[w][j+3];
            float d4 = sd[w][j+4], d5 = sd[w][j+5], d6 = sd[w][j+6], d7 = sd[w][j+7];
            acc = fmaf(d0, v0, acc); acc = fmaf(d1, v1, acc);
            acc = fmaf(d2, v2, acc); acc = fmaf(d3, v3, acc);
            acc = fmaf(d4, v4, acc); acc = fmaf(d5, v5, acc);
            acc = fmaf(d6, v6, acc); acc = fmaf(d7, v7, acc);
        }
    }
    float o = di * acc + b[lane];
    if (RELU) o = fmaxf(o, 0.f);
    __builtin_nontemporal_store(f2bf(o), &outbuf[(size_t)wid * 64 + lane]);
}

// ---------------- decode: z is bf16 [N x 64] ----------------
__global__ void k_decode(const int* __restrict__ eli, const ushort16* __restrict__ z,
                         float* __restrict__ out) {
    int e = blockIdx.x * blockDim.x + threadIdx.x;
    if (e >= N_EL) return;
    int a = eli[e];
    int b = eli[N_EL + e];
    const uint4* za = (const uint4*)(z + (size_t)a * 64);
    const uint4* zb = (const uint4*)(z + (size_t)b * 64);
    float acc = 0.0f;
#pragma unroll
    for (int i = 0; i < 8; ++i) {
        uint4 va = za[i], vb = zb[i];
        acc += bf_lo(va.x) * bf_lo(vb.x) + bf_hi(va.x) * bf_hi(vb.x);
        acc += bf_lo(va.y) * bf_lo(vb.y) + bf_hi(va.y) * bf_hi(vb.y);
        acc += bf_lo(va.z) * bf_lo(vb.z) + bf_hi(va.z) * bf_hi(vb.z);
        acc += bf_lo(va.w) * bf_lo(vb.w) + bf_hi(va.w) * bf_hi(vb.w);
    }
    out[e] = acc;
}

extern "C" void kernel_launch(void* const* d_in, const int* in_sizes, int n_in,
                              void* d_out, int out_size, void* d_ws, size_t ws_size,
                              hipStream_t stream) {
    const float* x   = (const float*)d_in[0];
    const int*   ei  = (const int*)d_in[1];
    const int*   eli = (const int*)d_in[2];
    const float* W1  = (const float*)d_in[3];
    const float* b1  = (const float*)d_in[4];
    const float* W2  = (const float*)d_in[5];
    const float* b2  = (const float*)d_in[6];
    const float* W3  = (const float*)d_in[7];
    const float* b3  = (const float*)d_in[8];
    float* out = (float*)d_out;

    const int* srcA = ei;
    const int* dstA = ei + N_EDGES;

    // workspace layout (bytes) — non-overlapping:
    //   dinv   [0, 400,000)   rowptr [1M, +400K+4)
    //   bsum [1888K) boff [1896K)   col [2M, 8.4M)   r [9M, 15.4M)
    //   t    [16M, +25.6M)  bf16 N x 128
    //   aggb [48M, +25.6M)  bf16 N x 128 (layers), N x 64 (final z)  -> ends 73.6M
    //   cpad [80M, +6.4M)   line-padded counters (1 int per 64B)
    char* ws = (char*)d_ws;
    float*    dinv   = (float*)   (ws + 0);
    int*      rowptr = (int*)     (ws + (1024u << 10));
    int*      bsum   = (int*)     (ws + (1888u << 10));
    int*      boff   = (int*)     (ws + (1896u << 10));
    int*      col    = (int*)     (ws + (2048u << 10));
    int*      r      = (int*)     (ws + (9u << 20));
    ushort16* t      = (ushort16*)(ws + (16u << 20));
    ushort16* aggb   = (ushort16*)(ws + (48u << 20));
    int*      cpad   = (int*)     (ws + (80u << 20));

    const int B = 256;
    const int gE  = (N_EDGES + B - 1) / B;    // 6250
    const int gG  = (N_NODES * 64 + B - 1) / B;
    const int gEL = (N_EL + B - 1) / B;

    // ---- CSR build overlapped with GEMM1 ----
    hipMemsetAsync(cpad, 0, (size_t)N_NODES * CPAD * sizeof(int), stream);
    k_fat1<<<GT_GEMM + gE, B, 0, stream>>>(x, W1, t, dstA, cpad, r);
    k_scan1<<<NB_SCAN, 256, 0, stream>>>(cpad, rowptr, bsum, dinv);
    k_scan2<<<1, 512, 0, stream>>>(bsum, boff);
    k_scan3<<<NB_SCAN, 256, 0, stream>>>(rowptr, boff);
    k_fill2<<<gE, B, 0, stream>>>(srcA, dstA, rowptr, r, col);

    // ---- layer 1 aggregation ----
    k_gather128<true><<<gG, B, 0, stream>>>(rowptr, col, dinv, (const uint32*)t, b1,
                                            (uint32*)aggb);
    // ---- layer 2 ----
    k_gemm_mfma<128, ushort16><<<GT_GEMM, B, 0, stream>>>(aggb, W2, t);
    k_gather128<true><<<gG, B, 0, stream>>>(rowptr, col, dinv, (const uint32*)t, b2,
                                            (uint32*)aggb);
    // ---- layer 3 ----
    k_gemm_mfma<64, ushort16><<<GT_GEMM, B, 0, stream>>>(aggb, W3, t);
    k_gather64<false><<<gG, B, 0, stream>>>(rowptr, col, dinv, t, b3, aggb);

    // ---- decode ----
    k_decode<<<gEL, B, 0, stream>>>(eli, aggb, out);
}

// Round 2
// 431.104 us; speedup vs baseline: 1.1375x; 1.0421x over previous
//
#include <hip/hip_runtime.h>
#include <hip/hip_bf16.h>

#define N_NODES 100000
#define N_EDGES 1600000
#define N_EL    200000
// D_IN = D_HID = 128; layer-3 output D = 64. f32 inputs, int32 indices, f32 output.
// Round 17:
//  (1) fat1: interleave rank/gemm blocks (bid%5) for true temporal overlap
//      (round-16 put all gemm blocks first -> two serial phases, 88us).
//  (2) W staging: thread packs 8 bf16 (j innermost) -> 1 ds_write_b128,
//      consecutive lanes -> consecutive 16B -> bank-conflict-free
//      (was 2.4M conflicts/dispatch from 2B scatter writes).
//  (3) gemm2/gemm3 epilogues prescale by dinv[node] -> gathers 2/3 drop the
//      dinv[src] gather + sd[] LDS entirely; padded lanes hit zeroed row
//      t[N_NODES] (layer-3 t uses row stride 128 so one 256B pad serves both).

#define NB_SCAN ((N_NODES + 255) / 256)   // 391
#define CPAD 16                            // ints per counter line
#define GT_GEMM ((N_NODES + 63) / 64)      // 1563 gemm blocks (64 rows each)
#define GE_RANK ((N_EDGES + 255) / 256)    // 6250 rank blocks

typedef unsigned int uint32;
typedef unsigned short ushort16;
typedef __attribute__((ext_vector_type(8))) short short8;   // 8 bf16 (4 VGPRs)
typedef __attribute__((ext_vector_type(4))) float f32x4;

static __device__ __forceinline__ ushort16 f2bf(float f) {
    uint32 u = __float_as_uint(f);
    u += 0x7fffu + ((u >> 16) & 1u);      // RNE
    return (ushort16)(u >> 16);
}
static __device__ __forceinline__ float bf_lo(uint32 p) { return __uint_as_float(p << 16); }
static __device__ __forceinline__ float bf_hi(uint32 p) { return __uint_as_float(p & 0xffff0000u); }
static __device__ __forceinline__ float bf2f(ushort16 h) { return __uint_as_float((uint32)h << 16); }

// ---------------- scan pass 1 (+ dinv); deg read from padded counters ----------------
__global__ void k_scan1(const int* __restrict__ cpad, int* __restrict__ rowptr,
                        int* __restrict__ bsum, float* __restrict__ dinv) {
    __shared__ int s[256];
    int t = threadIdx.x;
    int i = blockIdx.x * 256 + t;
    int v = (i < N_NODES) ? cpad[(size_t)i * CPAD] : 0;
    if (i < N_NODES) dinv[i] = 1.0f / sqrtf((float)(v + 1));   // +1 self-loop
    s[t] = v;
    __syncthreads();
    for (int off = 1; off < 256; off <<= 1) {
        int u = (t >= off) ? s[t - off] : 0;
        __syncthreads();
        s[t] += u;
        __syncthreads();
    }
    if (i < N_NODES) rowptr[i] = s[t] - v;          // exclusive, local
    if (t == 255) bsum[blockIdx.x] = s[255];
}

__global__ void k_scan2(const int* __restrict__ bsum, int* __restrict__ boff) {
    __shared__ int s[512];
    int t = threadIdx.x;
    int v = (t < NB_SCAN) ? bsum[t] : 0;
    s[t] = v;
    __syncthreads();
    for (int off = 1; off < 512; off <<= 1) {
        int u = (t >= off) ? s[t - off] : 0;
        __syncthreads();
        s[t] += u;
        __syncthreads();
    }
    if (t < NB_SCAN) boff[t] = s[t] - v;            // exclusive
    if (t == NB_SCAN - 1) boff[NB_SCAN] = s[t];     // total
}

__global__ void k_scan3(int* __restrict__ rowptr, const int* __restrict__ boff) {
    int i = blockIdx.x * 256 + threadIdx.x;
    if (i < N_NODES) rowptr[i] += boff[blockIdx.x];
    if (i == 0) rowptr[N_NODES] = boff[NB_SCAN];
}

// ---------------- pass 2: atomic-free CSR fill ----------------
__global__ void k_fill2(const int* __restrict__ src, const int* __restrict__ dst,
                        const int* __restrict__ rowptr, const int* __restrict__ r,
                        int* __restrict__ col) {
    int e = blockIdx.x * blockDim.x + threadIdx.x;
    if (e >= N_EDGES) return;
    int pos = rowptr[dst[e]] + r[e];
    __builtin_nontemporal_store(src[e], &col[pos]);
}

// ---------------- A-fragment loaders ----------------
static __device__ __forceinline__ short8 load_afrag(const float* arow, int off) {
    float4 a0 = *(const float4*)(arow + off);
    float4 a1 = *(const float4*)(arow + off + 4);
    short8 af;
    af[0] = (short)f2bf(a0.x); af[1] = (short)f2bf(a0.y);
    af[2] = (short)f2bf(a0.z); af[3] = (short)f2bf(a0.w);
    af[4] = (short)f2bf(a1.x); af[5] = (short)f2bf(a1.y);
    af[6] = (short)f2bf(a1.z); af[7] = (short)f2bf(a1.w);
    return af;
}
static __device__ __forceinline__ short8 load_afrag(const ushort16* arow, int off) {
    return *(const short8*)(arow + off);   // 16B aligned
}

// ---- MFMA GEMM body: t[n,0:D] = bf16( [dinv[n]] * (A[n,:128] @ W[128,D]) ) ----
// Output row stride OS (shorts). SCALE: multiply by dinv[n] in epilogue.
template <int D, typename AT, bool SCALE, int OS>
static __device__ __forceinline__ void gemm_body(int bid, const AT* __restrict__ A,
        const float* __restrict__ W, const float* __restrict__ dinv,
        ushort16* __restrict__ C) {
    constexpr int NT = D / 16;                 // 8 (D=128) or 4 (D=64)
    constexpr int LNT = (NT == 8) ? 3 : 2;
    __shared__ short sB[4 * NT * 64 * 8];      // 32 KB / 16 KB

    int tid = threadIdx.x;

    // stage W -> LDS in B-fragment order; j (8 consecutive shorts) packed per
    // thread -> ds_write_b128, consecutive lanes -> consecutive 16B chunks.
    constexpr int COMBOS = 4 * 4 * NT * 16;    // 2048 / 1024
    for (int cc = tid; cc < COMBOS; cc += 256) {
        int nn = cc & 15;
        int nt = (cc >> 4) & (NT - 1);
        int q  = (cc >> (4 + LNT)) & 3;
        int kt = cc >> (6 + LNT);
        short8 pk;
#pragma unroll
        for (int j = 0; j < 8; ++j)
            pk[j] = (short)f2bf(W[(kt * 32 + q * 8 + j) * D + nt * 16 + nn]);
        *(short8*)&sB[(((kt * NT + nt) * 64) + q * 16 + nn) * 8] = pk;
    }
    __syncthreads();

    int w = tid >> 6;
    int l = tid & 63;
    int q = l >> 4;
    int nn15 = l & 15;
    int m0 = bid * 64 + w * 16;

    f32x4 acc[NT];
#pragma unroll
    for (int i = 0; i < NT; ++i) acc[i] = (f32x4){0.f, 0.f, 0.f, 0.f};

    int m = m0 + nn15;
    m = min(m, N_NODES - 1);                    // tail clamp (loads only)
    const AT* arow = A + (size_t)m * 128;

#pragma unroll
    for (int kt = 0; kt < 4; ++kt) {
        short8 af = load_afrag(arow, kt * 32 + q * 8);
#pragma unroll
        for (int nt = 0; nt < NT; ++nt) {
            short8 bf = *(const short8*)&sB[((kt * NT + nt) * 64 + l) * 8];
            acc[nt] = __builtin_amdgcn_mfma_f32_16x16x32_bf16(af, bf, acc[nt], 0, 0, 0);
        }
    }

    // epilogue: node = m0 + q*4 + r, col = nt*16 + nn15
    float4 dv;
    if constexpr (SCALE) dv = *(const float4*)(dinv + m0 + 4 * q);
    const float* dvp = (const float*)&dv;
#pragma unroll
    for (int nt = 0; nt < NT; ++nt) {
#pragma unroll
        for (int r = 0; r < 4; ++r) {
            int node = m0 + q * 4 + r;
            if (node < N_NODES) {
                float val = acc[nt][r];
                if constexpr (SCALE) val *= dvp[r];
                C[(size_t)node * OS + nt * 16 + nn15] = f2bf(val);
            }
        }
    }
}

template <int D, typename AT, bool SCALE, int OS>
__global__ __launch_bounds__(256, 4) void k_gemm_mfma(const AT* __restrict__ A,
        const float* __restrict__ W, const float* __restrict__ dinv,
        ushort16* __restrict__ C) {
    gemm_body<D, AT, SCALE, OS>(blockIdx.x, A, W, dinv, C);
}

// ---------------- fat kernel: GEMM1 + rank, INTERLEAVED (bid%5==0 -> gemm) ------
__global__ __launch_bounds__(256, 4) void k_fat1(const float* __restrict__ A,
        const float* __restrict__ W, ushort16* __restrict__ C,
        const int* __restrict__ dst, int* __restrict__ cpad, int* __restrict__ r) {
    unsigned bid = blockIdx.x;
    unsigned g = bid / 5u;
    if (bid % 5u == 0u) {                       // 1563 gemm blocks
        gemm_body<128, float, false, 128>(g, A, W, nullptr, C);
    } else {                                    // 6250 rank blocks
        unsigned rid = g * 4u + (bid % 5u) - 1u;
        unsigned e = rid * 256u + threadIdx.x;
        if (e < N_EDGES) r[e] = atomicAdd(&cpad[(size_t)dst[e] * CPAD], 1);
    }
}

// ---------------- gather, D=128: one wave/node, bulk-col + LDS broadcast ---------
// WEIGHTED: t unscaled, weight = dinv[src] (layer 1).
// !WEIGHTED: t prescaled by dinv[src]; pads -> zero row t[N_NODES].
template <bool RELU, bool WEIGHTED>
__global__ void k_gather128(const int* __restrict__ rowptr, const int* __restrict__ col,
                            const float* __restrict__ dinv, const uint32* __restrict__ t,
                            const float* __restrict__ b, uint32* __restrict__ outbuf) {
    __shared__ int   sc[4][64];
    __shared__ float sd[4][64];
    int tid = threadIdx.x;
    unsigned wid = (blockIdx.x * 256u + tid) >> 6;
    if (wid >= N_NODES) return;
    int w = tid >> 6;
    int lane = tid & 63;
    int beg = rowptr[wid], end = rowptr[wid + 1];
    float di = dinv[wid];
    uint32 p = t[(size_t)wid * 64 + lane];
    float ax, ay;
    if (WEIGHTED) { ax = di * bf_lo(p); ay = di * bf_hi(p); }   // self-loop term
    else          { ax = bf_lo(p);      ay = bf_hi(p);      }
    for (int base = beg; base < end; base += 64) {
        int cnt = min(end - base, 64);
        int c = WEIGHTED ? 0 : N_NODES;
        if (lane < cnt) c = col[base + lane];            // 1 coalesced load / 64 edges
        sc[w][lane] = c;
        if (WEIGHTED) sd[w][lane] = (lane < cnt) ? dinv[c] : 0.f;
        int nb = (cnt + 7) >> 3;                          // padded 8-batches
        for (int j8 = 0; j8 < nb; ++j8) {
            int j = j8 << 3;
            int s0 = sc[w][j+0], s1 = sc[w][j+1], s2 = sc[w][j+2], s3 = sc[w][j+3];
            int s4 = sc[w][j+4], s5 = sc[w][j+5], s6 = sc[w][j+6], s7 = sc[w][j+7];
            uint32 v0 = t[(size_t)s0 * 64 + lane];
            uint32 v1 = t[(size_t)s1 * 64 + lane];
            uint32 v2 = t[(size_t)s2 * 64 + lane];
            uint32 v3 = t[(size_t)s3 * 64 + lane];
            uint32 v4 = t[(size_t)s4 * 64 + lane];
            uint32 v5 = t[(size_t)s5 * 64 + lane];
            uint32 v6 = t[(size_t)s6 * 64 + lane];
            uint32 v7 = t[(size_t)s7 * 64 + lane];
            if (WEIGHTED) {
                float d0 = sd[w][j+0], d1 = sd[w][j+1], d2 = sd[w][j+2], d3 = sd[w][j+3];
                float d4 = sd[w][j+4], d5 = sd[w][j+5], d6 = sd[w][j+6], d7 = sd[w][j+7];
                ax = fmaf(d0, bf_lo(v0), ax); ay = fmaf(d0, bf_hi(v0), ay);
                ax = fmaf(d1, bf_lo(v1), ax); ay = fmaf(d1, bf_hi(v1), ay);
                ax = fmaf(d2, bf_lo(v2), ax); ay = fmaf(d2, bf_hi(v2), ay);
                ax = fmaf(d3, bf_lo(v3), ax); ay = fmaf(d3, bf_hi(v3), ay);
                ax = fmaf(d4, bf_lo(v4), ax); ay = fmaf(d4, bf_hi(v4), ay);
                ax = fmaf(d5, bf_lo(v5), ax); ay = fmaf(d5, bf_hi(v5), ay);
                ax = fmaf(d6, bf_lo(v6), ax); ay = fmaf(d6, bf_hi(v6), ay);
                ax = fmaf(d7, bf_lo(v7), ax); ay = fmaf(d7, bf_hi(v7), ay);
            } else {
                ax += (bf_lo(v0) + bf_lo(v1)) + (bf_lo(v2) + bf_lo(v3))
                    + ((bf_lo(v4) + bf_lo(v5)) + (bf_lo(v6) + bf_lo(v7)));
                ay += (bf_hi(v0) + bf_hi(v1)) + (bf_hi(v2) + bf_hi(v3))
                    + ((bf_hi(v4) + bf_hi(v5)) + (bf_hi(v6) + bf_hi(v7)));
            }
        }
    }
    float2 bb = ((const float2*)b)[lane];
    float ox = di * ax + bb.x;
    float oy = di * ay + bb.y;
    if (RELU) { ox = fmaxf(ox, 0.f); oy = fmaxf(oy, 0.f); }
    __builtin_nontemporal_store((uint32)f2bf(ox) | ((uint32)f2bf(oy) << 16),
                                &outbuf[(size_t)wid * 64 + lane]);
}

// ---- gather, D=64: t prescaled, row stride 128 shorts; pads -> zero row --------
template <bool RELU>
__global__ void k_gather64(const int* __restrict__ rowptr, const int* __restrict__ col,
                           const float* __restrict__ dinv, const ushort16* __restrict__ t,
                           const float* __restrict__ b, ushort16* __restrict__ outbuf) {
    __shared__ int sc[4][64];
    int tid = threadIdx.x;
    unsigned wid = (blockIdx.x * 256u + tid) >> 6;
    if (wid >= N_NODES) return;
    int w = tid >> 6;
    int lane = tid & 63;
    int beg = rowptr[wid], end = rowptr[wid + 1];
    float di = dinv[wid];
    float acc = bf2f(t[(size_t)wid * 128 + lane]);   // self-loop (prescaled)
    for (int base = beg; base < end; base += 64) {
        int cnt = min(end - base, 64);
        int c = N_NODES;
        if (lane < cnt) c = col[base + lane];
        sc[w][lane] = c;
        int nb = (cnt + 7) >> 3;
        for (int j8 = 0; j8 < nb; ++j8) {
            int j = j8 << 3;
            int s0 = sc[w][j+0], s1 = sc[w][j+1], s2 = sc[w][j+2], s3 = sc[w][j+3];
            int s4 = sc[w][j+4], s5 = sc[w][j+5], s6 = sc[w][j+6], s7 = sc[w][j+7];
            float v0 = bf2f(t[(size_t)s0 * 128 + lane]);
            float v1 = bf2f(t[(size_t)s1 * 128 + lane]);
            float v2 = bf2f(t[(size_t)s2 * 128 + lane]);
            float v3 = bf2f(t[(size_t)s3 * 128 + lane]);
            float v4 = bf2f(t[(size_t)s4 * 128 + lane]);
            float v5 = bf2f(t[(size_t)s5 * 128 + lane]);
            float v6 = bf2f(t[(size_t)s6 * 128 + lane]);
            float v7 = bf2f(t[(size_t)s7 * 128 + lane]);
            acc += (v0 + v1) + (v2 + v3) + ((v4 + v5) + (v6 + v7));
        }
    }
    float o = di * acc + b[lane];
    if (RELU) o = fmaxf(o, 0.f);
    __builtin_nontemporal_store(f2bf(o), &outbuf[(size_t)wid * 64 + lane]);
}

// ---------------- decode: z is bf16 [N x 64] ----------------
__global__ void k_decode(const int* __restrict__ eli, const ushort16* __restrict__ z,
                         float* __restrict__ out) {
    int e = blockIdx.x * blockDim.x + threadIdx.x;
    if (e >= N_EL) return;
    int a = eli[e];
    int b = eli[N_EL + e];
    const uint4* za = (const uint4*)(z + (size_t)a * 64);
    const uint4* zb = (const uint4*)(z + (size_t)b * 64);
    float acc = 0.0f;
#pragma unroll
    for (int i = 0; i < 8; ++i) {
        uint4 va = za[i], vb = zb[i];
        acc += bf_lo(va.x) * bf_lo(vb.x) + bf_hi(va.x) * bf_hi(vb.x);
        acc += bf_lo(va.y) * bf_lo(vb.y) + bf_hi(va.y) * bf_hi(vb.y);
        acc += bf_lo(va.z) * bf_lo(vb.z) + bf_hi(va.z) * bf_hi(vb.z);
        acc += bf_lo(va.w) * bf_lo(vb.w) + bf_hi(va.w) * bf_hi(vb.w);
    }
    out[e] = acc;
}

extern "C" void kernel_launch(void* const* d_in, const int* in_sizes, int n_in,
                              void* d_out, int out_size, void* d_ws, size_t ws_size,
                              hipStream_t stream) {
    const float* x   = (const float*)d_in[0];
    const int*   ei  = (const int*)d_in[1];
    const int*   eli = (const int*)d_in[2];
    const float* W1  = (const float*)d_in[3];
    const float* b1  = (const float*)d_in[4];
    const float* W2  = (const float*)d_in[5];
    const float* b2  = (const float*)d_in[6];
    const float* W3  = (const float*)d_in[7];
    const float* b3  = (const float*)d_in[8];
    float* out = (float*)d_out;

    const int* srcA = ei;
    const int* dstA = ei + N_EDGES;

    // workspace layout (bytes) — non-overlapping:
    //   dinv   [0, 400,000)   rowptr [1M, +400K+4)
    //   bsum [1888K) boff [1896K)   col [2M, 8.4M)   r [9M, 15.4M)
    //   t    [16M, +25.6M+256)  bf16 N x 128 (+ zero pad row N_NODES)
    //   aggb [48M, +25.6M)  bf16 N x 128 (layers), N x 64 (final z)
    //   cpad [80M, +6.4M)   line-padded counters (1 int per 64B)
    char* ws = (char*)d_ws;
    float*    dinv   = (float*)   (ws + 0);
    int*      rowptr = (int*)     (ws + (1024u << 10));
    int*      bsum   = (int*)     (ws + (1888u << 10));
    int*      boff   = (int*)     (ws + (1896u << 10));
    int*      col    = (int*)     (ws + (2048u << 10));
    int*      r      = (int*)     (ws + (9u << 20));
    ushort16* t      = (ushort16*)(ws + (16u << 20));
    ushort16* aggb   = (ushort16*)(ws + (48u << 20));
    int*      cpad   = (int*)     (ws + (80u << 20));

    const int B = 256;
    const int gG  = (N_NODES * 64 + B - 1) / B;
    const int gEL = (N_EL + B - 1) / B;

    // ---- CSR build overlapped with GEMM1 (interleaved block roles) ----
    hipMemsetAsync(cpad, 0, (size_t)N_NODES * CPAD * sizeof(int), stream);
    hipMemsetAsync((char*)t + (size_t)N_NODES * 256, 0, 256, stream);  // pad row
    k_fat1<<<GT_GEMM + GE_RANK, B, 0, stream>>>(x, W1, t, dstA, cpad, r);
    k_scan1<<<NB_SCAN, 256, 0, stream>>>(cpad, rowptr, bsum, dinv);
    k_scan2<<<1, 512, 0, stream>>>(bsum, boff);
    k_scan3<<<NB_SCAN, 256, 0, stream>>>(rowptr, boff);
    k_fill2<<<GE_RANK, B, 0, stream>>>(srcA, dstA, rowptr, r, col);

    // ---- layer 1 aggregation (weighted: t unscaled) ----
    k_gather128<true, true><<<gG, B, 0, stream>>>(rowptr, col, dinv, (const uint32*)t,
                                                  b1, (uint32*)aggb);
    // ---- layer 2 (t prescaled by dinv in epilogue) ----
    k_gemm_mfma<128, ushort16, true, 128><<<GT_GEMM, B, 0, stream>>>(aggb, W2, dinv, t);
    k_gather128<true, false><<<gG, B, 0, stream>>>(rowptr, col, dinv, (const uint32*)t,
                                                   b2, (uint32*)aggb);
    // ---- layer 3 (t prescaled, row stride 128 so pad row is shared) ----
    k_gemm_mfma<64, ushort16, true, 128><<<GT_GEMM, B, 0, stream>>>(aggb, W3, dinv, t);
    k_gather64<false><<<gG, B, 0, stream>>>(rowptr, col, dinv, t, b3, aggb);

    // ---- decode ----
    k_decode<<<gEL, B, 0, stream>>>(eli, aggb, out);
}